// Round 5
// baseline (164.825 us; speedup 1.0000x reference)
//
#include <hip/hip_runtime.h>
#include <hip/hip_bf16.h>

#define HW 16384   // 128*128
#define CC 64
#define BB 4

typedef __attribute__((ext_vector_type(8))) short bf8;   // 8 bf16 (4 VGPRs)
typedef __attribute__((ext_vector_type(4))) float f4;    // MFMA C/D frag

static __device__ __forceinline__ float bf2f(unsigned short u) {
    return __uint_as_float(((unsigned)u) << 16);
}
static __device__ __forceinline__ unsigned short f2bf(float f) {
    __hip_bfloat16 h = __float2bfloat16(f);   // RNE
    return *reinterpret_cast<unsigned short*>(&h);
}

// ---------------------------------------------------------------------------
// K0 (merged prep + transpose):
//  blocks [0,216):   wA[32][576], Wal[64][576] bf16 weight repack
//  blocks [216,472): xT[b*HW+hw][c] bf16 (channels contiguous, 128B rows)
// ---------------------------------------------------------------------------
__global__ __launch_bounds__(256) void k_prep_tx(const float* __restrict__ x,
                                                 const float* __restrict__ w_off,
                                                 const float* __restrict__ w_align,
                                                 unsigned short* __restrict__ xT,
                                                 unsigned short* __restrict__ wA,
                                                 unsigned short* __restrict__ Wal) {
    int bx = blockIdx.x;
    if (bx < 216) {
        int i = bx * 256 + threadIdx.x;
        if (i < 32 * 576) {
            int m = i / 576, r = i - m * 576, t = r >> 6, c = r & 63;
            float v = (m < 27) ? w_off[m * 576 + c * 9 + t] : 0.f;
            wA[i] = f2bf(v);
        } else {
            int j = i - 32 * 576;   // j < 64*576 by grid construction
            int o = j / 576, r = j - o * 576, t = r >> 6, c = r & 63;
            Wal[j] = f2bf(w_align[o * 576 + c * 9 + t]);
        }
    } else {
        int idx = (bx - 216) * 256 + threadIdx.x;      // b*HW + hw
        const float* xp = x + (size_t)(idx >> 14) * CC * HW + (idx & (HW - 1));
        unsigned short* op = xT + (size_t)idx * CC;
#pragma unroll
        for (int c8 = 0; c8 < 8; c8++) {
            unsigned short u[8];
#pragma unroll
            for (int j = 0; j < 8; j++) u[j] = f2bf(xp[(size_t)(c8 * 8 + j) * HW]);
            uint4 q;
            q.x = u[0] | ((unsigned)u[1] << 16);
            q.y = u[2] | ((unsigned)u[3] << 16);
            q.z = u[4] | ((unsigned)u[5] << 16);
            q.w = u[6] | ((unsigned)u[7] << 16);
            *(uint4*)(op + c8 * 8) = q;
        }
    }
}

// ---------------------------------------------------------------------------
// K1: offset conv as 9-tap shifted MFMA GEMM. M=32 (27 used), K=576, N=65536.
// ---------------------------------------------------------------------------
__global__ __launch_bounds__(256) void k_conv(const unsigned short* __restrict__ xT,
                                              const unsigned short* __restrict__ wA,
                                              const float* __restrict__ b_off,
                                              float* __restrict__ off) {
    int t = threadIdx.x, lane = t & 63, wv = t >> 6;
    int quad = lane >> 4, col = lane & 15;
    int n = blockIdx.x * 64 + wv * 16 + col;           // global pixel
    int b = n >> 14, hw = n & (HW - 1), h = hw >> 7, w = hw & 127;
    const unsigned short* xTb = xT + (size_t)b * HW * CC;
    const bf8 zero = {0, 0, 0, 0, 0, 0, 0, 0};

    f4 acc0 = {0.f, 0.f, 0.f, 0.f};
    f4 acc1 = {0.f, 0.f, 0.f, 0.f};
#pragma unroll
    for (int tap = 0; tap < 9; tap++) {
        int dyt = tap / 3 - 1, dxt = tap - (tap / 3) * 3 - 1;
        int hs = h + dyt, ws = w + dxt;
        bool valid = ((unsigned)hs < 128u) && ((unsigned)ws < 128u);
        int hc = min(max(hs, 0), 127), wc = min(max(ws, 0), 127);
        const unsigned short* src = xTb + ((size_t)(hc * 128 + wc)) * CC + quad * 8;
        bf8 b0 = *(const bf8*)(src);
        bf8 b1 = *(const bf8*)(src + 32);
        b0 = valid ? b0 : zero;
        b1 = valid ? b1 : zero;
        bf8 a00 = *(const bf8*)(wA + (size_t)col * 576 + tap * 64 + quad * 8);
        bf8 a01 = *(const bf8*)(wA + (size_t)col * 576 + tap * 64 + 32 + quad * 8);
        bf8 a10 = *(const bf8*)(wA + (size_t)(col + 16) * 576 + tap * 64 + quad * 8);
        bf8 a11 = *(const bf8*)(wA + (size_t)(col + 16) * 576 + tap * 64 + 32 + quad * 8);
        acc0 = __builtin_amdgcn_mfma_f32_16x16x32_bf16(a00, b0, acc0, 0, 0, 0);
        acc1 = __builtin_amdgcn_mfma_f32_16x16x32_bf16(a10, b0, acc1, 0, 0, 0);
        acc0 = __builtin_amdgcn_mfma_f32_16x16x32_bf16(a01, b1, acc0, 0, 0, 0);
        acc1 = __builtin_amdgcn_mfma_f32_16x16x32_bf16(a11, b1, acc1, 0, 0, 0);
    }
#pragma unroll
    for (int i = 0; i < 4; i++) {
        int o0 = quad * 4 + i;                          // 0..15, always < 27
        {
            float v = acc0[i] + b_off[o0];
            if (o0 >= 18) v = 2.f / (1.f + __expf(-v));
            off[((size_t)b * 27 + o0) * HW + hw] = v;
        }
        int o1 = 16 + o0;
        if (o1 < 27) {
            float v = acc1[i] + b_off[o1];
            if (o1 >= 18) v = 2.f / (1.f + __expf(-v));
            off[((size_t)b * 27 + o1) * HW + hw] = v;
        }
    }
}

// ---------------------------------------------------------------------------
// K2 (fused): sampling -> LDS -> einsum MFMA, pipelined over 3 tap-groups.
// Block = 256 threads / 32 pixels. LDS = 12.3 KB S3 + 3.4 KB offL
// -> 8 blocks/CU = 32 waves (wave cap) for latency hiding via TLP.
// S3 holds 3 taps of B-fragments as 16B blocks, XOR-swizzled:
//   block index f = (kl*32 + p)*8 + (cg ^ (p&7))
// write phase: lanes sharing p have distinct f%8  -> conflict-free
// read  phase: lanes sharing quad have f%8 = cgc^(col&7) -> conflict-free
// ---------------------------------------------------------------------------
__global__ __launch_bounds__(256, 8) void k_fused(const unsigned short* __restrict__ xT,
                                                  const float* __restrict__ off,
                                                  const unsigned short* __restrict__ Wal,
                                                  const float* __restrict__ b_align,
                                                  float* __restrict__ wten) {
    __shared__ __align__(16) unsigned short S3[768 * 8];   // 12288 B
    __shared__ float offL[27][32];                         // 3456 B

    int t = threadIdx.x, lane = t & 63, wv = t >> 6;
    int n0 = blockIdx.x * 32;                 // global pixel base
    int b = n0 >> 14, hw0 = n0 & (HW - 1);
    const unsigned short* xTb = xT + (size_t)b * HW * CC;

    // ---- stage offsets ----
    for (int i = t; i < 27 * 32; i += 256) {
        int r = i >> 5, p = i & 31;
        offL[r][p] = off[((size_t)b * 27 + r) * HW + hw0 + p];
    }

    // phase-A ids
    int cg = lane & 7;
    int pA = wv * 8 + (lane >> 3);
    int hwA = hw0 + pA, hA = hwA >> 7, wAx = hwA & 127;
    const unsigned short* baseA = xTb + cg * 8;

    // phase-B ids
    int quad = lane >> 4, col = lane & 15;
    int pg = wv & 1, mh = wv >> 1;
    int pp = pg * 16 + col;
    f4 acc0 = {0.f, 0.f, 0.f, 0.f};
    f4 acc1 = {0.f, 0.f, 0.f, 0.f};
    const unsigned short* wrow = Wal + (size_t)(mh * 32 + col) * 576 + quad * 8;

    __syncthreads();

#pragma unroll
    for (int g = 0; g < 3; g++) {
        if (g) __syncthreads();               // prev group's reads complete
        // ---- phase A: sample taps 3g..3g+2 into S3 ----
        uint4 q[3][4];
        float cw[3][4];
#pragma unroll
        for (int kk = 0; kk < 3; kk++) {
            int k = 3 * g + kk;
            float dy = offL[2 * k][pA];
            float dx = offL[2 * k + 1][pA];
            float m  = offL[18 + k][pA];
            int k3 = k / 3;
            float ys = (float)(hA + k3 - 1) + dy;
            float xs = (float)(wAx + (k - 3 * k3) - 1) + dx;
            float y0f = floorf(ys), x0f = floorf(xs);
            float fy = ys - y0f, fx = xs - x0f;
            int y0 = (int)y0f, x0 = (int)x0f;
            int y1 = y0 + 1, x1 = x0 + 1;
            bool vy0 = (unsigned)y0 < 128u, vy1 = (unsigned)y1 < 128u;
            bool vx0 = (unsigned)x0 < 128u, vx1 = (unsigned)x1 < 128u;
            int cy0 = min(max(y0, 0), 127), cy1 = min(max(y1, 0), 127);
            int cx0 = min(max(x0, 0), 127), cx1 = min(max(x1, 0), 127);
            cw[kk][0] = (1.f - fy) * (1.f - fx) * ((vy0 && vx0) ? m : 0.f);
            cw[kk][1] = (1.f - fy) * fx         * ((vy0 && vx1) ? m : 0.f);
            cw[kk][2] = fy * (1.f - fx)         * ((vy1 && vx0) ? m : 0.f);
            cw[kk][3] = fy * fx                 * ((vy1 && vx1) ? m : 0.f);
            q[kk][0] = *(const uint4*)(baseA + ((size_t)(cy0 * 128 + cx0)) * CC);
            q[kk][1] = *(const uint4*)(baseA + ((size_t)(cy0 * 128 + cx1)) * CC);
            q[kk][2] = *(const uint4*)(baseA + ((size_t)(cy1 * 128 + cx0)) * CC);
            q[kk][3] = *(const uint4*)(baseA + ((size_t)(cy1 * 128 + cx1)) * CC);
        }
#pragma unroll
        for (int kk = 0; kk < 3; kk++) {
            const unsigned short* u00 = (const unsigned short*)&q[kk][0];
            const unsigned short* u01 = (const unsigned short*)&q[kk][1];
            const unsigned short* u10 = (const unsigned short*)&q[kk][2];
            const unsigned short* u11 = (const unsigned short*)&q[kk][3];
            unsigned short ov[8];
#pragma unroll
            for (int j = 0; j < 8; j++) {
                float v = cw[kk][0] * bf2f(u00[j]) + cw[kk][1] * bf2f(u01[j])
                        + cw[kk][2] * bf2f(u10[j]) + cw[kk][3] * bf2f(u11[j]);
                ov[j] = f2bf(v);
            }
            uint4 qq;
            qq.x = ov[0] | ((unsigned)ov[1] << 16);
            qq.y = ov[2] | ((unsigned)ov[3] << 16);
            qq.z = ov[4] | ((unsigned)ov[5] << 16);
            qq.w = ov[6] | ((unsigned)ov[7] << 16);
            int f = (kk * 32 + pA) * 8 + (cg ^ (pA & 7));   // swizzled 16B block
            *(uint4*)(S3 + (size_t)f * 8) = qq;
        }
        __syncthreads();

        // ---- phase B: 6 MFMA steps for this group ----
#pragma unroll
        for (int s = 0; s < 6; s++) {
            int kl = s >> 1, cgc = ((s & 1) << 2) + quad;
            int f = (kl * 32 + pp) * 8 + (cgc ^ (pp & 7));
            bf8 bfrag = *(const bf8*)(S3 + (size_t)f * 8);
            int sg = g * 6 + s;
            bf8 a0 = *(const bf8*)(wrow + sg * 32);
            bf8 a1 = *(const bf8*)(wrow + (size_t)16 * 576 + sg * 32);
            acc0 = __builtin_amdgcn_mfma_f32_16x16x32_bf16(a0, bfrag, acc0, 0, 0, 0);
            acc1 = __builtin_amdgcn_mfma_f32_16x16x32_bf16(a1, bfrag, acc1, 0, 0, 0);
        }
    }

    // ---- epilogue: bias + exp(sigmoid) ----
#pragma unroll
    for (int i = 0; i < 4; i++) {
        {
            int o = mh * 32 + quad * 4 + i;
            float u = acc0[i] + b_align[o];
            float sg = 1.f / (1.f + __expf(-u));
            wten[((size_t)b * CC + o) * HW + hw0 + pp] = __expf(sg);
        }
        {
            int o = mh * 32 + 16 + quad * 4 + i;
            float u = acc1[i] + b_align[o];
            float sg = 1.f / (1.f + __expf(-u));
            wten[((size_t)b * CC + o) * HW + hw0 + pp] = __expf(sg);
        }
    }
}

// ---------------------------------------------------------------------------
// K3: out = pool3s2(w*x)/pool3s2(w) (the /9 cancels; zero-pad taps drop out).
// ---------------------------------------------------------------------------
__global__ __launch_bounds__(256) void k_pool(const float* __restrict__ x,
                                              const float* __restrict__ wten,
                                              float* __restrict__ out) {
    int idx = blockIdx.x * 256 + threadIdx.x;
    int ow = idx & 63;
    int oh = (idx >> 6) & 63;
    int bc = idx >> 12;
    const float* wp = wten + (size_t)bc * HW;
    const float* xp = x + (size_t)bc * HW;
    float num = 0.f, den = 0.f;
#pragma unroll
    for (int iy = 0; iy < 3; iy++) {
        int y = 2 * oh + iy - 1;
        if ((unsigned)y >= 128u) continue;
#pragma unroll
        for (int ix = 0; ix < 3; ix++) {
            int xc = 2 * ow + ix - 1;
            if ((unsigned)xc >= 128u) continue;
            float wv = wp[y * 128 + xc];
            float xv = xp[y * 128 + xc];
            num = fmaf(wv, xv, num);
            den += wv;
        }
    }
    out[idx] = num / den;
}

// ---------------------------------------------------------------------------
extern "C" void kernel_launch(void* const* d_in, const int* in_sizes, int n_in,
                              void* d_out, int out_size, void* d_ws, size_t ws_size,
                              hipStream_t stream) {
    const float* x       = (const float*)d_in[0];
    const float* w_off   = (const float*)d_in[1];
    const float* b_off   = (const float*)d_in[2];
    const float* w_align = (const float*)d_in[3];
    const float* b_align = (const float*)d_in[4];
    float* out = (float*)d_out;

    // workspace layout (~32.4 MB):
    char* p = (char*)d_ws;
    float* off  = (float*)p;                  p += (size_t)BB * 27 * HW * 4;  // 7.08 MB
    float* wten = (float*)p;                  p += (size_t)BB * CC * HW * 4;  // 16.78 MB
    unsigned short* xT  = (unsigned short*)p; p += (size_t)BB * HW * CC * 2;  // 8.39 MB
    unsigned short* wA  = (unsigned short*)p; p += 32 * 576 * 2;              // 36.9 KB
    unsigned short* Wal = (unsigned short*)p;                                 // 73.7 KB

    k_prep_tx<<<dim3(472), dim3(256), 0, stream>>>(x, w_off, w_align, xT, wA, Wal);
    k_conv<<<dim3(1024), dim3(256), 0, stream>>>(xT, wA, b_off, off);
    k_fused<<<dim3(2048), dim3(256), 0, stream>>>(xT, off, Wal, b_align, wten);
    k_pool<<<dim3(4096), dim3(256), 0, stream>>>(x, wten, out);
}

// Round 6
// 135.611 us; speedup vs baseline: 1.2154x; 1.2154x over previous
//
#include <hip/hip_runtime.h>
#include <hip/hip_bf16.h>

#define HW 16384   // 128*128
#define CC 64
#define BB 4

typedef __attribute__((ext_vector_type(8))) short bf8;   // 8 bf16 (4 VGPRs)
typedef __attribute__((ext_vector_type(4))) float f4;    // MFMA C/D frag

static __device__ __forceinline__ float bf2f(unsigned short u) {
    return __uint_as_float(((unsigned)u) << 16);
}
static __device__ __forceinline__ unsigned short f2bf(float f) {
    __hip_bfloat16 h = __float2bfloat16(f);   // RNE
    return *reinterpret_cast<unsigned short*>(&h);
}

// ---------------------------------------------------------------------------
// K0: weight repack (blocks 0..215) + x transpose via LDS (blocks 216..1239).
//  wA  [32][576] bf16 : wA[m][t*64+c] = w_off[m][c][t]   (rows 27..31 zero)
//  Wal [64][576] bf16 : Wal[o][t*64+c] = w_align[o][c][t]
//  xT  [b*HW+hw][c]   : channels contiguous (128B rows)
// Transpose: coalesced 4B reads -> T32[p][cp] (stride 33: bank (p+cp)%32,
// conflict-free writes) -> coalesced 16B row writes.
// ---------------------------------------------------------------------------
__global__ __launch_bounds__(256) void k_prep_tx(const float* __restrict__ x,
                                                 const float* __restrict__ w_off,
                                                 const float* __restrict__ w_align,
                                                 unsigned short* __restrict__ xT,
                                                 unsigned short* __restrict__ wA,
                                                 unsigned short* __restrict__ Wal) {
    __shared__ unsigned T32[64 * 33];   // 8448 B
    int bx = blockIdx.x, t = threadIdx.x;
    if (bx < 216) {
        int i = bx * 256 + t;
        if (i < 32 * 576) {
            int m = i / 576, r = i - m * 576, tt = r >> 6, c = r & 63;
            float v = (m < 27) ? w_off[m * 576 + c * 9 + tt] : 0.f;
            wA[i] = f2bf(v);
        } else {
            int j = i - 32 * 576;   // j < 64*576 by grid construction
            int o = j / 576, r = j - o * 576, tt = r >> 6, c = r & 63;
            Wal[j] = f2bf(w_align[o * 576 + c * 9 + tt]);
        }
        return;
    }
    int pix0 = (bx - 216) * 64;
    int b = pix0 >> 14, hw0 = pix0 & (HW - 1);
    const float* xb = x + (size_t)b * CC * HW + hw0;
#pragma unroll
    for (int u = 0; u < 8; u++) {
        int i = t + 256 * u;                 // 2048 = 32 cp x 64 p
        int cp = i >> 6, p = i & 63;
        float v0 = xb[(size_t)(2 * cp) * HW + p];
        float v1 = xb[(size_t)(2 * cp + 1) * HW + p];
        T32[p * 33 + cp] = (unsigned)f2bf(v0) | ((unsigned)f2bf(v1) << 16);
    }
    __syncthreads();
#pragma unroll
    for (int u = 0; u < 2; u++) {
        int i = t + 256 * u;                 // 512 = 64 p x 8 q
        int p = i >> 3, q = i & 7;
        uint4 qq;
        qq.x = T32[p * 33 + q * 4 + 0];
        qq.y = T32[p * 33 + q * 4 + 1];
        qq.z = T32[p * 33 + q * 4 + 2];
        qq.w = T32[p * 33 + q * 4 + 3];
        *(uint4*)(xT + ((size_t)b * HW + hw0 + p) * CC + q * 8) = qq;
    }
}

// ---------------------------------------------------------------------------
// K1: offset conv, 9-tap shifted MFMA GEMM. Weights staged ONCE in LDS
// (rows padded 576->584 bf16: bank (4(col+quad))%32, <=2-way = free).
// Barrier-free tap loop; wave = 16 px, 32 outputs (27 used).
// ---------------------------------------------------------------------------
__global__ __launch_bounds__(256, 4) void k_conv(const unsigned short* __restrict__ xT,
                                                 const unsigned short* __restrict__ wA,
                                                 const float* __restrict__ b_off,
                                                 float* __restrict__ off) {
    __shared__ __align__(16) unsigned short WL[32 * 584];   // 37376 B
    int t = threadIdx.x, lane = t & 63, wv = t >> 6;
    int quad = lane >> 4, col = lane & 15;
#pragma unroll
    for (int u = 0; u < 9; u++) {
        int idx = t + 256 * u;               // 2304 = 32 rows x 72 uint4
        int row = idx / 72, jb = idx - row * 72;
        *(uint4*)(WL + row * 584 + jb * 8) = ((const uint4*)wA)[idx];
    }
    __syncthreads();

    int n = blockIdx.x * 64 + wv * 16 + col;           // global pixel
    int b = n >> 14, hw = n & (HW - 1), h = hw >> 7, w = hw & 127;
    const unsigned short* xTb = xT + (size_t)b * HW * CC;
    const bf8 zero = {0, 0, 0, 0, 0, 0, 0, 0};

    f4 acc0 = {0.f, 0.f, 0.f, 0.f};
    f4 acc1 = {0.f, 0.f, 0.f, 0.f};
#pragma unroll
    for (int tap = 0; tap < 9; tap++) {
        int dyt = tap / 3 - 1, dxt = tap - (tap / 3) * 3 - 1;
        int hs = h + dyt, ws = w + dxt;
        bool valid = ((unsigned)hs < 128u) && ((unsigned)ws < 128u);
        int hc = min(max(hs, 0), 127), wc = min(max(ws, 0), 127);
        const unsigned short* src = xTb + ((size_t)(hc * 128 + wc)) * CC + quad * 8;
        bf8 b0 = *(const bf8*)(src);
        bf8 b1 = *(const bf8*)(src + 32);
        b0 = valid ? b0 : zero;
        b1 = valid ? b1 : zero;
        const unsigned short* l0 = WL + col * 584 + tap * 64 + quad * 8;
        const unsigned short* l1 = WL + (col + 16) * 584 + tap * 64 + quad * 8;
        acc0 = __builtin_amdgcn_mfma_f32_16x16x32_bf16(*(const bf8*)l0, b0, acc0, 0, 0, 0);
        acc1 = __builtin_amdgcn_mfma_f32_16x16x32_bf16(*(const bf8*)l1, b0, acc1, 0, 0, 0);
        acc0 = __builtin_amdgcn_mfma_f32_16x16x32_bf16(*(const bf8*)(l0 + 32), b1, acc0, 0, 0, 0);
        acc1 = __builtin_amdgcn_mfma_f32_16x16x32_bf16(*(const bf8*)(l1 + 32), b1, acc1, 0, 0, 0);
    }
#pragma unroll
    for (int i = 0; i < 4; i++) {
        int o0 = quad * 4 + i;                          // 0..15, always < 27
        {
            float v = acc0[i] + b_off[o0];
            if (o0 >= 18) v = 2.f / (1.f + __expf(-v));
            off[((size_t)b * 27 + o0) * HW + hw] = v;
        }
        int o1 = 16 + o0;
        if (o1 < 27) {
            float v = acc1[i] + b_off[o1];
            if (o1 >= 18) v = 2.f / (1.f + __expf(-v));
            off[((size_t)b * 27 + o1) * HW + hw] = v;
        }
    }
}

// ---------------------------------------------------------------------------
// K2 (fused, barrier-free main loop): lane (quad,col) samples channels
// quad*8 + h*32 of pixel col -> values land directly in B-frag registers
// (A and B frags share the lane layout for 16x16x32). Wave = 16 pixels x
// all 64 outputs (4 m-tiles). Weights double-buffered in LDS per 3-tap
// group (rows padded 192->200 bf16 -> <=2-way bank aliasing = free).
// Only 3 __syncthreads per block, each fencing a LONG phase.
// ---------------------------------------------------------------------------
__global__ __launch_bounds__(256, 3) void k_fused(const unsigned short* __restrict__ xT,
                                                  const float* __restrict__ off,
                                                  const unsigned short* __restrict__ Wal,
                                                  const float* __restrict__ b_align,
                                                  float* __restrict__ wten) {
    __shared__ __align__(16) unsigned short WB[2][64 * 200];   // 2 x 25600 B

    int t = threadIdx.x, lane = t & 63, wv = t >> 6;
    int quad = lane >> 4, col = lane & 15;
    int pix0 = blockIdx.x * 64;
    int b = pix0 >> 14;
    int px = (pix0 & (HW - 1)) + wv * 16 + col;        // lane's pixel (within b)
    int h = px >> 7, w = px & 127;
    const unsigned short* xTb = xT + (size_t)b * HW * CC;
    const float* offp = off + (size_t)b * 27 * HW + px;

    // stage weight group 0
#pragma unroll
    for (int u = 0; u < 6; u++) {
        int idx = t + 256 * u;               // 1536 = 64 rows x 24 uint4
        int row = idx / 24, jb = idx - row * 24;
        *(uint4*)(&WB[0][row * 200 + jb * 8]) = ((const uint4*)Wal)[row * 72 + jb];
    }
    __syncthreads();

    f4 acc[4];
#pragma unroll
    for (int mt = 0; mt < 4; mt++) acc[mt] = (f4){0.f, 0.f, 0.f, 0.f};

#pragma unroll
    for (int g = 0; g < 3; g++) {
        if (g < 2) {   // prefetch next weight group into the other buffer
#pragma unroll
            for (int u = 0; u < 6; u++) {
                int idx = t + 256 * u;
                int row = idx / 24, jb = idx - row * 24;
                *(uint4*)(&WB[(g + 1) & 1][row * 200 + jb * 8]) =
                    ((const uint4*)Wal)[row * 72 + (g + 1) * 24 + jb];
            }
        }
        const unsigned short* WLg = WB[g & 1];
#pragma unroll
        for (int kk = 0; kk < 3; kk++) {
            int k = 3 * g + kk;
            float dy = offp[(size_t)(2 * k) * HW];
            float dx = offp[(size_t)(2 * k + 1) * HW];
            float m  = offp[(size_t)(18 + k) * HW];
            int k3 = k / 3;
            float ys = (float)(h + k3 - 1) + dy;
            float xs = (float)(w + (k - 3 * k3) - 1) + dx;
            float y0f = floorf(ys), x0f = floorf(xs);
            float fy = ys - y0f, fx = xs - x0f;
            int y0 = (int)y0f, x0 = (int)x0f;
            int y1 = y0 + 1, x1 = x0 + 1;
            bool vy0 = (unsigned)y0 < 128u, vy1 = (unsigned)y1 < 128u;
            bool vx0 = (unsigned)x0 < 128u, vx1 = (unsigned)x1 < 128u;
            int cy0 = min(max(y0, 0), 127), cy1 = min(max(y1, 0), 127);
            int cx0 = min(max(x0, 0), 127), cx1 = min(max(x1, 0), 127);
            float w00 = (1.f - fy) * (1.f - fx) * ((vy0 && vx0) ? m : 0.f);
            float w01 = (1.f - fy) * fx         * ((vy0 && vx1) ? m : 0.f);
            float w10 = fy * (1.f - fx)         * ((vy1 && vx0) ? m : 0.f);
            float w11 = fy * fx                 * ((vy1 && vx1) ? m : 0.f);

            const unsigned short* c00 = xTb + ((size_t)(cy0 * 128 + cx0)) * CC + quad * 8;
            const unsigned short* c01 = xTb + ((size_t)(cy0 * 128 + cx1)) * CC + quad * 8;
            const unsigned short* c10 = xTb + ((size_t)(cy1 * 128 + cx0)) * CC + quad * 8;
            const unsigned short* c11 = xTb + ((size_t)(cy1 * 128 + cx1)) * CC + quad * 8;
            // 8 independent 16B gathers (2 halves x 4 corners)
            uint4 qa0 = *(const uint4*)(c00),      qa1 = *(const uint4*)(c01);
            uint4 qa2 = *(const uint4*)(c10),      qa3 = *(const uint4*)(c11);
            uint4 qb0 = *(const uint4*)(c00 + 32), qb1 = *(const uint4*)(c01 + 32);
            uint4 qb2 = *(const uint4*)(c10 + 32), qb3 = *(const uint4*)(c11 + 32);

            bf8 bfrag[2];
#pragma unroll
            for (int h2 = 0; h2 < 2; h2++) {
                const unsigned short* u00 = (const unsigned short*)(h2 ? &qb0 : &qa0);
                const unsigned short* u01 = (const unsigned short*)(h2 ? &qb1 : &qa1);
                const unsigned short* u10 = (const unsigned short*)(h2 ? &qb2 : &qa2);
                const unsigned short* u11 = (const unsigned short*)(h2 ? &qb3 : &qa3);
                unsigned short ov[8];
#pragma unroll
                for (int j = 0; j < 8; j++) {
                    float v = w00 * bf2f(u00[j]) + w01 * bf2f(u01[j])
                            + w10 * bf2f(u10[j]) + w11 * bf2f(u11[j]);
                    ov[j] = f2bf(v);
                }
                bfrag[h2] = *(const bf8*)ov;
            }
#pragma unroll
            for (int h2 = 0; h2 < 2; h2++) {
#pragma unroll
                for (int mt = 0; mt < 4; mt++) {
                    const bf8 a = *(const bf8*)(WLg + (size_t)(mt * 16 + col) * 200
                                                + kk * 64 + h2 * 32 + quad * 8);
                    acc[mt] = __builtin_amdgcn_mfma_f32_16x16x32_bf16(a, bfrag[h2], acc[mt], 0, 0, 0);
                }
            }
        }
        if (g < 2) __syncthreads();
    }

    // ---- epilogue: bias + exp(sigmoid) ----
    float* wb = wten + (size_t)b * CC * HW + px;
#pragma unroll
    for (int mt = 0; mt < 4; mt++)
#pragma unroll
        for (int i = 0; i < 4; i++) {
            int o = mt * 16 + quad * 4 + i;
            float u = acc[mt][i] + b_align[o];
            float sg = 1.f / (1.f + __expf(-u));
            wb[(size_t)o * HW] = __expf(sg);
        }
}

// ---------------------------------------------------------------------------
// K3: out = pool3s2(w*x)/pool3s2(w) (the /9 cancels; zero-pad taps drop out).
// ---------------------------------------------------------------------------
__global__ __launch_bounds__(256) void k_pool(const float* __restrict__ x,
                                              const float* __restrict__ wten,
                                              float* __restrict__ out) {
    int idx = blockIdx.x * 256 + threadIdx.x;
    int ow = idx & 63;
    int oh = (idx >> 6) & 63;
    int bc = idx >> 12;
    const float* wp = wten + (size_t)bc * HW;
    const float* xp = x + (size_t)bc * HW;
    float num = 0.f, den = 0.f;
#pragma unroll
    for (int iy = 0; iy < 3; iy++) {
        int y = 2 * oh + iy - 1;
        if ((unsigned)y >= 128u) continue;
#pragma unroll
        for (int ix = 0; ix < 3; ix++) {
            int xc = 2 * ow + ix - 1;
            if ((unsigned)xc >= 128u) continue;
            float wv = wp[y * 128 + xc];
            float xv = xp[y * 128 + xc];
            num = fmaf(wv, xv, num);
            den += wv;
        }
    }
    out[idx] = num / den;
}

// ---------------------------------------------------------------------------
extern "C" void kernel_launch(void* const* d_in, const int* in_sizes, int n_in,
                              void* d_out, int out_size, void* d_ws, size_t ws_size,
                              hipStream_t stream) {
    const float* x       = (const float*)d_in[0];
    const float* w_off   = (const float*)d_in[1];
    const float* b_off   = (const float*)d_in[2];
    const float* w_align = (const float*)d_in[3];
    const float* b_align = (const float*)d_in[4];
    float* out = (float*)d_out;

    // workspace layout (~32.4 MB):
    char* p = (char*)d_ws;
    float* off  = (float*)p;                  p += (size_t)BB * 27 * HW * 4;  // 7.08 MB
    float* wten = (float*)p;                  p += (size_t)BB * CC * HW * 4;  // 16.78 MB
    unsigned short* xT  = (unsigned short*)p; p += (size_t)BB * HW * CC * 2;  // 8.39 MB
    unsigned short* wA  = (unsigned short*)p; p += 32 * 576 * 2;              // 36.9 KB
    unsigned short* Wal = (unsigned short*)p;                                 // 73.7 KB

    k_prep_tx<<<dim3(1240), dim3(256), 0, stream>>>(x, w_off, w_align, xT, wA, Wal);
    k_conv<<<dim3(1024), dim3(256), 0, stream>>>(xT, wA, b_off, off);
    k_fused<<<dim3(1024), dim3(256), 0, stream>>>(xT, off, Wal, b_align, wten);
    k_pool<<<dim3(4096), dim3(256), 0, stream>>>(x, wten, out);
}